// Round 1
// baseline (273.663 us; speedup 1.0000x reference)
//
#include <hip/hip_runtime.h>

#define LOG2E 1.4426950408889634f

// One thread per (b,l) row.
// pred row = 132 floats = 4 corners x 33 logits. Row stride 528 B = 33*16 -> 16B aligned.
// scores/out row = 80 floats = 320 B -> 16B aligned.
__global__ __launch_bounds__(256) void lqe_fused(
    const float* __restrict__ scores,
    const float* __restrict__ pred,
    const float* __restrict__ w1,   // [20][64]
    const float* __restrict__ b1,   // [64]
    const float* __restrict__ w2,   // [64]
    const float* __restrict__ b2,   // [1]
    float* __restrict__ out,
    int nrows)
{
    const int row = blockIdx.x * blockDim.x + threadIdx.x;
    if (row >= nrows) return;

    const float* rp = pred + (size_t)row * 132;

    float stat[20];
#pragma unroll
    for (int c = 0; c < 4; ++c) {
        const int fstart = 33 * c;          // first float index of this corner
        const int vstart = fstart >> 2;     // float4 index (0,8,16,24)
        const int off    = fstart & 3;      // 0,1,2,3
        const float4* vp = reinterpret_cast<const float4*>(rp) + vstart;

        // 9 aligned float4 loads cover the 33 floats (+ up to 3 lead floats).
        float xs[36];
#pragma unroll
        for (int k = 0; k < 9; ++k) {
            float4 v = vp[k];
            xs[4*k+0] = v.x; xs[4*k+1] = v.y; xs[4*k+2] = v.z; xs[4*k+3] = v.w;
        }

        // Branchless top-4 (sorted desc) of the 33 logits.
        float t0 = -1e30f, t1 = -1e30f, t2 = -1e30f, t3 = -1e30f;
#pragma unroll
        for (int j = 0; j < 33; ++j) {
            float v  = xs[off + j];
            float r0 = fminf(t0, v);  t0 = fmaxf(t0, v);
            float r1 = fminf(t1, r0); t1 = fmaxf(t1, r0);
            float r2 = fminf(t2, r1); t2 = fmaxf(t2, r1);
            t3 = fmaxf(t3, r2);
        }

        // Softmax denominator with max-shift (t0 is the max).
        float denom = 0.f;
#pragma unroll
        for (int j = 0; j < 33; ++j)
            denom += __builtin_amdgcn_exp2f((xs[off + j] - t0) * LOG2E);
        float rd = __builtin_amdgcn_rcpf(denom);

        // top-4 probabilities (softmax is monotonic -> top logits = top probs)
        float p0 = rd;  // exp(0) * rd
        float p1 = __builtin_amdgcn_exp2f((t1 - t0) * LOG2E) * rd;
        float p2 = __builtin_amdgcn_exp2f((t2 - t0) * LOG2E) * rd;
        float p3 = __builtin_amdgcn_exp2f((t3 - t0) * LOG2E) * rd;

        stat[c*5+0] = p0;
        stat[c*5+1] = p1;
        stat[c*5+2] = p2;
        stat[c*5+3] = p3;
        stat[c*5+4] = (p0 + p1 + p2 + p3) * 0.25f;
    }

    // MLP: h = silu(stat @ w1 + b1); q = h @ w2 + b2.
    // All w1/b1/w2/b2 indices are thread-uniform -> compiler emits s_load,
    // SGPR operands are free in the v_fma stream.
    float hacc[64];
#pragma unroll
    for (int h = 0; h < 64; ++h) hacc[h] = b1[h];
#pragma unroll
    for (int i = 0; i < 20; ++i) {
        const float si = stat[i];
#pragma unroll
        for (int h = 0; h < 64; ++h)
            hacc[h] = fmaf(si, w1[i*64 + h], hacc[h]);
    }
    float q = b2[0];
#pragma unroll
    for (int h = 0; h < 64; ++h) {
        float v  = hacc[h];
        float sg = __builtin_amdgcn_rcpf(1.f + __builtin_amdgcn_exp2f(-v * LOG2E));
        q = fmaf(v * sg, w2[h], q);
    }

    // out = scores + q (broadcast over the 80 channels), 20 aligned float4s.
    const float4* sp = reinterpret_cast<const float4*>(scores + (size_t)row * 80);
    float4*       op = reinterpret_cast<float4*>(out + (size_t)row * 80);
#pragma unroll
    for (int k = 0; k < 20; ++k) {
        float4 s = sp[k];
        s.x += q; s.y += q; s.z += q; s.w += q;
        op[k] = s;
    }
}

extern "C" void kernel_launch(void* const* d_in, const int* in_sizes, int n_in,
                              void* d_out, int out_size, void* d_ws, size_t ws_size,
                              hipStream_t stream) {
    const float* scores = (const float*)d_in[0];
    const float* pred   = (const float*)d_in[1];
    const float* w1     = (const float*)d_in[2];
    const float* b1     = (const float*)d_in[3];
    const float* w2     = (const float*)d_in[4];
    const float* b2     = (const float*)d_in[5];
    float* out = (float*)d_out;

    const int nrows = in_sizes[1] / 132;          // 800000
    const int block = 256;
    const int grid  = (nrows + block - 1) / block; // 3125

    hipLaunchKernelGGL(lqe_fused, dim3(grid), dim3(block), 0, stream,
                       scores, pred, w1, b1, w2, b2, out, nrows);
}

// Round 2
// 176.024 us; speedup vs baseline: 1.5547x; 1.5547x over previous
//
#include <hip/hip_runtime.h>

#define LOG2E 1.4426950408889634f

typedef __attribute__((address_space(3))) unsigned int lds_u32_t;
typedef const __attribute__((address_space(1))) unsigned int glb_u32_t;

// Block = 256 threads <-> 64 rows. 4 threads per row (one per corner).
// pred row = 132 floats (4 corners x 33 logits); block tile = 64*132 floats = 33792 B, 16B-aligned.
// scores/out row = 80 floats; block tile = 1280 float4.
__global__ __launch_bounds__(256, 4) void lqe_fused2(
    const float* __restrict__ scores,
    const float* __restrict__ pred,
    const float* __restrict__ w1,   // [20][64]
    const float* __restrict__ b1,   // [64]
    const float* __restrict__ w2,   // [64]
    const float* __restrict__ b2,   // [1]
    float* __restrict__ out)
{
    __shared__ float predS[64 * 132];   // 33792 B, linear (matches global layout)
    __shared__ float wS[1412];          // w1[0..1279] b1[1280..1343] w2[1344..1407] b2[1408]
    __shared__ float qS[64];

    const int t   = threadIdx.x;
    const int bid = blockIdx.x;

    // ---- prefetch this block's scores into regs (consumed in epilogue) ----
    const size_t f4base = (size_t)bid * 1280;    // 64 rows * 20 float4
    const float4* sv4 = reinterpret_cast<const float4*>(scores) + f4base;
    float4 sv[5];
#pragma unroll
    for (int k = 0; k < 5; ++k) sv[k] = sv4[t + 256 * k];

    // ---- stage pred tile (2112 float4) via async global->LDS, width 16 ----
    {
        const float* gp  = pred + (size_t)bid * 8448;
        const int wbase  = t & ~63;     // wave-uniform part of the f4 index
        const int lane   = t & 63;
#pragma unroll
        for (int k = 0; k < 8; ++k) {
            const int f4 = 256 * k + wbase;    // wave-uniform
            __builtin_amdgcn_global_load_lds(
                (glb_u32_t*)(gp + 4 * (f4 + lane)),   // per-lane global src
                (lds_u32_t*)(predS + 4 * f4),         // wave-uniform LDS base (+lane*16 by HW)
                16, 0, 0);
        }
        if (t < 64) {                          // tail: f4 2048..2111, wave 0 only
            __builtin_amdgcn_global_load_lds(
                (glb_u32_t*)(gp + 4 * (2048 + lane)),
                (lds_u32_t*)(predS + 4 * 2048),
                16, 0, 0);
        }
    }

    // ---- stage MLP params (1409 floats), coalesced scalar copies ----
#pragma unroll
    for (int k = 0; k < 5; ++k) wS[t + 256 * k] = w1[t + 256 * k];     // 1280
    if (t < 64)  { wS[1280 + t] = b1[t]; wS[1344 + t] = w2[t]; }
    if (t == 0)  { wS[1408] = b2[0]; }

    __syncthreads();   // drains vmcnt (global_load_lds) + lgkm

    // ---- corner phase: thread (r = t/4, c = t%4) owns one corner ----
    const int r = t >> 2;
    const int c = t & 3;
    const float* xp = predS + r * 132 + c * 33;   // LDS addr = 33*lane + j -> conflict-free
    float xs[33];
#pragma unroll
    for (int j = 0; j < 33; ++j) xs[j] = xp[j];

    // branchless top-4 (sorted desc)
    float t0 = -1e30f, t1 = -1e30f, t2 = -1e30f, t3 = -1e30f;
#pragma unroll
    for (int j = 0; j < 33; ++j) {
        float v  = xs[j];
        float r0 = fminf(t0, v);  t0 = fmaxf(t0, v);
        float r1 = fminf(t1, r0); t1 = fmaxf(t1, r0);
        float r2 = fminf(t2, r1); t2 = fmaxf(t2, r1);
        t3 = fmaxf(t3, r2);
    }

    float denom = 0.f;
#pragma unroll
    for (int j = 0; j < 33; ++j)
        denom += __builtin_amdgcn_exp2f((xs[j] - t0) * LOG2E);
    float rd = __builtin_amdgcn_rcpf(denom);

    float s5[5];
    s5[0] = rd;
    s5[1] = __builtin_amdgcn_exp2f((t1 - t0) * LOG2E) * rd;
    s5[2] = __builtin_amdgcn_exp2f((t2 - t0) * LOG2E) * rd;
    s5[3] = __builtin_amdgcn_exp2f((t3 - t0) * LOG2E) * rd;
    s5[4] = (s5[0] + s5[1] + s5[2] + s5[3]) * 0.25f;

    // ---- exchange: every thread in the quad gets all 20 stats of its row ----
    const int qbase = (t & 63) & ~3;
    float stat[20];
#pragma unroll
    for (int i = 0; i < 20; ++i)
        stat[i] = __shfl(s5[i % 5], qbase + i / 5, 64);   // static reg index, quad-local

    // ---- MLP: each thread computes hidden units [16c .. 16c+15] ----
    float hacc[16];
    {
        const float4* b1v = reinterpret_cast<const float4*>(wS + 1280 + 16 * c);
#pragma unroll
        for (int k = 0; k < 4; ++k) {
            float4 b = b1v[k];
            hacc[4*k+0] = b.x; hacc[4*k+1] = b.y; hacc[4*k+2] = b.z; hacc[4*k+3] = b.w;
        }
    }
#pragma unroll
    for (int i = 0; i < 20; ++i) {
        const float si = stat[i];
        const float4* wv = reinterpret_cast<const float4*>(wS + i * 64 + 16 * c);
#pragma unroll
        for (int k = 0; k < 4; ++k) {
            float4 w = wv[k];
            hacc[4*k+0] = fmaf(si, w.x, hacc[4*k+0]);
            hacc[4*k+1] = fmaf(si, w.y, hacc[4*k+1]);
            hacc[4*k+2] = fmaf(si, w.z, hacc[4*k+2]);
            hacc[4*k+3] = fmaf(si, w.w, hacc[4*k+3]);
        }
    }

    float q = 0.f;
    {
        const float4* w2v = reinterpret_cast<const float4*>(wS + 1344 + 16 * c);
#pragma unroll
        for (int k = 0; k < 4; ++k) {
            float4 w = w2v[k];
#pragma unroll
            for (int e = 0; e < 4; ++e) {
                float v  = hacc[4*k+e];
                float sg = __builtin_amdgcn_rcpf(1.f + __builtin_amdgcn_exp2f(-v * LOG2E));
                float we = (e == 0) ? w.x : (e == 1) ? w.y : (e == 2) ? w.z : w.w;
                q = fmaf(v * sg, we, q);
            }
        }
    }
    q += __shfl_xor(q, 1, 64);
    q += __shfl_xor(q, 2, 64);
    q += wS[1408];
    if (c == 0) qS[r] = q;
    __syncthreads();

    // ---- epilogue: coalesced out = scores + q ----
    float4* ov4 = reinterpret_cast<float4*>(out) + f4base;
#pragma unroll
    for (int k = 0; k < 5; ++k) {
        const int idx = t + 256 * k;
        const float qq = qS[idx / 20];
        float4 s = sv[k];
        s.x += qq; s.y += qq; s.z += qq; s.w += qq;
        ov4[idx] = s;
    }
}

extern "C" void kernel_launch(void* const* d_in, const int* in_sizes, int n_in,
                              void* d_out, int out_size, void* d_ws, size_t ws_size,
                              hipStream_t stream) {
    const float* scores = (const float*)d_in[0];
    const float* pred   = (const float*)d_in[1];
    const float* w1     = (const float*)d_in[2];
    const float* b1     = (const float*)d_in[3];
    const float* w2     = (const float*)d_in[4];
    const float* b2     = (const float*)d_in[5];
    float* out = (float*)d_out;

    const int nrows = in_sizes[1] / 132;   // 800000; divisible by 64 (800000/64 = 12500)
    const int grid  = nrows / 64;

    hipLaunchKernelGGL(lqe_fused2, dim3(grid), dim3(256), 0, stream,
                       scores, pred, w1, b1, w2, b2, out);
}